// Round 1
// baseline (166086.694 us; speedup 1.0000x reference)
//
#include <hip/hip_runtime.h>
#include <math.h>

#define A_ 64
#define B_ 256
#define D_ 128
#define H_ 512
#define STOT 16384
#define NWG 32

// workspace layout (float offsets)
#define OFF_XT    0
#define N_XT      (A_*D_*B_)              // 2097152 floats: transposed input [t][k][b]
#define OFF_HT0   (OFF_XT + N_XT)         // encoder h ping  [j][b]
#define OFF_HT1   (OFF_HT0 + H_*B_)       // encoder h pong
#define OFF_CT    (OFF_HT1 + H_*B_)       // encoder c       [j][b]
#define OFF_HTAP  (OFF_CT + H_*B_)        // decoder h taps  [256][512]
#define OFF_HBUF  (OFF_HTAP + B_*H_)      // decoder h double buffer [2][512]
#define OFF_CINIT (OFF_HBUF + 2*H_)       // decoder initial c [512]
#define OFF_FLAGS (OFF_CINIT + H_)        // 32 int flags

__device__ __forceinline__ float sigf(float x) {
  return 1.0f / (1.0f + __expf(-x));
}

// ---------------------------------------------------------------------------
// init1: transpose input to XT[t][k][b], zero encoder h0/c0
// ---------------------------------------------------------------------------
__global__ void init1(const float* __restrict__ in0, float* __restrict__ ws) {
  float* XT  = ws + OFF_XT;
  float* HT0 = ws + OFF_HT0;
  float* CT  = ws + OFF_CT;
  int stride = gridDim.x * blockDim.x;
  for (int idx = blockIdx.x * blockDim.x + threadIdx.x; idx < N_XT; idx += stride) {
    int t = idx >> 15;            // / (128*256)
    int k = (idx >> 8) & 127;
    int b = idx & 255;
    XT[idx] = in0[t * (B_ * D_) + b * D_ + k];
    if (idx < H_ * B_) { HT0[idx] = 0.f; CT[idx] = 0.f; }
  }
}

// ---------------------------------------------------------------------------
// enc_step: one encoder LSTM timestep, fused GEMM (256x2048x640) + update.
// Grid (32 j-tiles of 16, 8 b-tiles of 32), 256 threads.
// H/C layout transposed: [j][b] so GEMM reads and update writes coalesce.
// ---------------------------------------------------------------------------
__global__ __launch_bounds__(256) void enc_step(
    const float* __restrict__ XT, const float* __restrict__ Wih,
    const float* __restrict__ Whh, const float* __restrict__ bih,
    const float* __restrict__ bhh, const float* __restrict__ Hin,
    float* __restrict__ Hout, float* __restrict__ C, int t) {
  __shared__ float Wt[16 * 68];   // [kk][row 0..63], padded stride 68 (16B aligned, conflict-free)
  __shared__ float XHt[16 * 32];  // [kk][b 0..31]
  __shared__ float gs[64 * 33];   // gate staging [row][b], pad 33
  const int tid = threadIdx.x;
  const int jt = blockIdx.x;      // j-tile: rows gate*512 + jt*16 + jj
  const int bt = blockIdx.y;      // b-tile of 32
  const int rr = tid >> 4;        // 0..15 -> local rows 4rr..4rr+3
  const int bb = tid & 15;        // -> local cols 2bb..2bb+1

  float acc[4][2];
#pragma unroll
  for (int i = 0; i < 4; ++i) {
    int r = 4 * rr + i;
    int Row = ((r >> 4) << 9) + (jt << 4) + (r & 15);
    float bv = bih[Row] + bhh[Row];
    acc[i][0] = bv; acc[i][1] = bv;
  }

  for (int kt = 0; kt < 40; ++kt) {
    int k0 = kt << 4;
    __syncthreads();
#pragma unroll
    for (int e = 0; e < 4; ++e) {       // load W tile (1024 elems)
      int idx = tid + (e << 8);
      int kk = idx & 15, r = idx >> 4;
      int Row = ((r >> 4) << 9) + (jt << 4) + (r & 15);
      int k = k0 + kk;
      float v = (k < D_) ? Wih[Row * D_ + k] : Whh[Row * H_ + (k - D_)];
      Wt[kk * 68 + r] = v;
    }
#pragma unroll
    for (int e = 0; e < 2; ++e) {       // load X/H tile (512 elems)
      int idx = tid + (e << 8);
      int kk = idx >> 5, b = idx & 31;
      int k = k0 + kk;
      int gb = (bt << 5) + b;
      float v = (k < D_) ? XT[(t * D_ + k) * B_ + gb] : Hin[(k - D_) * B_ + gb];
      XHt[kk * 32 + b] = v;
    }
    __syncthreads();
#pragma unroll
    for (int kk = 0; kk < 16; ++kk) {
      const float4 wv = *(const float4*)&Wt[kk * 68 + 4 * rr];
      const float2 xv = *(const float2*)&XHt[kk * 32 + 2 * bb];
      acc[0][0] += wv.x * xv.x; acc[0][1] += wv.x * xv.y;
      acc[1][0] += wv.y * xv.x; acc[1][1] += wv.y * xv.y;
      acc[2][0] += wv.z * xv.x; acc[2][1] += wv.z * xv.y;
      acc[3][0] += wv.w * xv.x; acc[3][1] += wv.w * xv.y;
    }
  }
  __syncthreads();
#pragma unroll
  for (int i = 0; i < 4; ++i) {
    gs[(4 * rr + i) * 33 + 2 * bb]     = acc[i][0];
    gs[(4 * rr + i) * 33 + 2 * bb + 1] = acc[i][1];
  }
  __syncthreads();
#pragma unroll
  for (int e = 0; e < 2; ++e) {         // LSTM cell update, 512 (j,b) pairs
    int idx = tid + (e << 8);
    int jj = idx >> 5, b = idx & 31;
    int gb = (bt << 5) + b;
    float iv = gs[jj * 33 + b];
    float fv = gs[(16 + jj) * 33 + b];
    float gv = gs[(32 + jj) * 33 + b];
    float ov = gs[(48 + jj) * 33 + b];
    int addr = ((jt << 4) + jj) * B_ + gb;
    float c = C[addr];
    c = sigf(fv) * c + sigf(iv) * tanhf(gv);
    C[addr] = c;
    Hout[addr] = sigf(ov) * tanhf(c);
  }
}

// ---------------------------------------------------------------------------
// init2: seed decoder state h=hN[255], c=cN[255]; zero flags
// ---------------------------------------------------------------------------
__global__ void init2(float* __restrict__ ws) {
  const float* Hfin = ws + OFF_HT0;   // after 64 steps final h lands in HT0
  const float* CT   = ws + OFF_CT;
  float* HBUF = ws + OFF_HBUF;
  float* CIN  = ws + OFF_CINIT;
  int* FLAGS  = (int*)(ws + OFF_FLAGS);
  int tid = threadIdx.x;
  if (tid < H_) {
    HBUF[H_ + tid] = Hfin[tid * B_ + 255];  // h_{-1} lives in buffer parity 1
    CIN[tid]       = CT[tid * B_ + 255];
  }
  if (tid < NWG) FLAGS[tid] = 0;
}

// ---------------------------------------------------------------------------
// decoder: persistent kernel, 32 WGs x 1024 threads, 16384 sequential steps.
// WG w owns h[16w..16w+16) -> 64 gate rows; weights register-resident.
// Per step: poll flags -> gather h (overlapped with x@Wih) -> FMA -> LDS
// reduce -> nonlinearity by 16 threads -> publish slice + release flag.
// ---------------------------------------------------------------------------
__global__ __launch_bounds__(1024, 4) void decoder(
    const float* __restrict__ in0, const float* __restrict__ Wih,
    const float* __restrict__ Whh, const float* __restrict__ bih,
    const float* __restrict__ bhh, float* __restrict__ ws) {
  float* HBUF = ws + OFF_HBUF;
  float* HTAP = ws + OFF_HTAP;
  const float* CIN = ws + OFF_CINIT;
  int* FLAGS = (int*)(ws + OFF_FLAGS);

  __shared__ float h_lds[H_];
  __shared__ float part[64 * 21];   // [row][wave], pad 21 => 2-way (free) conflicts
  __shared__ float gl[64];
  __shared__ float bl[64];
  __shared__ int ready;

  const int tid = threadIdx.x;
  const int w = blockIdx.x;
  const int v = tid >> 6;           // wave 0..15 -> col chunk
  const int l = tid & 63;           // lane -> local gate row
  const int R = ((l >> 4) << 9) + (w << 4) + (l & 15);  // global gate row

  float4 wa[8], wi2[2];
#pragma unroll
  for (int k = 0; k < 8; ++k)
    wa[k] = *(const float4*)&Whh[R * H_ + (v << 5) + 4 * k];
  wi2[0] = *(const float4*)&Wih[R * D_ + (v << 3)];
  wi2[1] = *(const float4*)&Wih[R * D_ + (v << 3) + 4];

  if (tid < 64) {
    int Rr = ((tid >> 4) << 9) + (w << 4) + (tid & 15);
    bl[tid] = bih[Rr] + bhh[Rr];
  }
  float c = 0.f;
  if (tid < 16) c = CIN[(w << 4) + tid];
  if (tid == 0) ready = -1;
  __syncthreads();

  for (int s = 0; s < STOT; ++s) {
    // ---- wait for h_{s-1} from all WGs (wave 0 polls; others spin on LDS) --
    if (v == 0) {
      for (;;) {
        int f = (l < NWG)
            ? __hip_atomic_load(&FLAGS[l], __ATOMIC_ACQUIRE, __HIP_MEMORY_SCOPE_AGENT)
            : s;
        if (__all(f >= s)) break;
        __builtin_amdgcn_s_sleep(1);
      }
      if (l == 0) *(volatile int*)&ready = s;
    }
    while (*(volatile int*)&ready < s) __builtin_amdgcn_s_sleep(1);

    // ---- gather h_{s-1} (device-coherent loads), overlap with x@Wih -------
    float hv = 0.f;
    if (tid < H_)
      hv = __hip_atomic_load(&HBUF[((s + 1) & 1) * H_ + tid],
                             __ATOMIC_RELAXED, __HIP_MEMORY_SCOPE_AGENT);
    const int tt = s & 63;
    const int bc = 255 - (s >> 6);
    const float* xp = in0 + (tt * B_ + bc) * D_ + (v << 3);
    float4 x0 = *(const float4*)xp;
    float4 x1 = *(const float4*)(xp + 4);
    float p = wi2[0].x * x0.x + wi2[0].y * x0.y + wi2[0].z * x0.z + wi2[0].w * x0.w
            + wi2[1].x * x1.x + wi2[1].y * x1.y + wi2[1].z * x1.z + wi2[1].w * x1.w;
    if (tid < H_) h_lds[tid] = hv;
    __syncthreads();

    // ---- tap h before processing a new column -----------------------------
    if ((s & 63) == 0 && tid < 16)
      HTAP[(s >> 6) * H_ + (w << 4) + tid] = h_lds[(w << 4) + tid];

    // ---- Whh @ h partial from register-resident weights -------------------
    const float* hp = &h_lds[v << 5];
#pragma unroll
    for (int k = 0; k < 8; ++k) {
      float4 h4 = *(const float4*)&hp[4 * k];
      p += wa[k].x * h4.x + wa[k].y * h4.y + wa[k].z * h4.z + wa[k].w * h4.w;
    }
    part[l * 21 + v] = p;
    __syncthreads();

    if (tid < 64) {                      // reduce 16 wave-partials per row
      float g = bl[tid];
#pragma unroll
      for (int j = 0; j < 16; ++j) g += part[tid * 21 + j];
      gl[tid] = g;
    }
    __syncthreads();

    if (tid < 16) {                      // cell update for own 16 h-elems
      float iv = sigf(gl[tid]);
      float fv = sigf(gl[16 + tid]);
      float gv = tanhf(gl[32 + tid]);
      float ov = sigf(gl[48 + tid]);
      c = fv * c + iv * gv;
      float hn = ov * tanhf(c);
      __hip_atomic_store(&HBUF[(s & 1) * H_ + (w << 4) + tid], hn,
                         __ATOMIC_RELAXED, __HIP_MEMORY_SCOPE_AGENT);
    }
    __threadfence();
    if (tid == 0)
      __hip_atomic_store(&FLAGS[w], s + 1, __ATOMIC_RELEASE, __HIP_MEMORY_SCOPE_AGENT);
  }
}

// ---------------------------------------------------------------------------
// out_proj: outs[255-b] = Htap[255-b] @ lin_W^T + lin_b, broadcast over a.
// ---------------------------------------------------------------------------
__global__ __launch_bounds__(128) void out_proj(
    const float* __restrict__ ws, const float* __restrict__ linW,
    const float* __restrict__ linb, float* __restrict__ out) {
  const float* HTAP = ws + OFF_HTAP;
  __shared__ float hs[H_];
  const int b = blockIdx.x;
  const int i = 255 - b;
  const int d = threadIdx.x;
  *(float4*)&hs[4 * d] = *(const float4*)&HTAP[i * H_ + 4 * d];
  __syncthreads();
  float acc = linb[d];
#pragma unroll 8
  for (int k = 0; k < H_; k += 4) {
    float4 w4 = *(const float4*)&linW[d * H_ + k];
    acc += w4.x * hs[k] + w4.y * hs[k + 1] + w4.z * hs[k + 2] + w4.w * hs[k + 3];
  }
  for (int a = 0; a < A_; ++a)
    out[(a * B_ + b) * D_ + d] = acc;
}

// ---------------------------------------------------------------------------
extern "C" void kernel_launch(void* const* d_in, const int* in_sizes, int n_in,
                              void* d_out, int out_size, void* d_ws, size_t ws_size,
                              hipStream_t stream) {
  const float* in0  = (const float*)d_in[0];
  const float* eWih = (const float*)d_in[1];
  const float* eWhh = (const float*)d_in[2];
  const float* ebih = (const float*)d_in[3];
  const float* ebhh = (const float*)d_in[4];
  const float* dWih = (const float*)d_in[5];
  const float* dWhh = (const float*)d_in[6];
  const float* dbih = (const float*)d_in[7];
  const float* dbhh = (const float*)d_in[8];
  const float* linW = (const float*)d_in[9];
  const float* linb = (const float*)d_in[10];
  float* ws = (float*)d_ws;
  float* out = (float*)d_out;

  init1<<<2048, 256, 0, stream>>>(in0, ws);

  const float* XT = ws + OFF_XT;
  for (int t = 0; t < 64; ++t) {
    float* Hin  = ws + ((t & 1) ? OFF_HT1 : OFF_HT0);
    float* Hout = ws + ((t & 1) ? OFF_HT0 : OFF_HT1);
    enc_step<<<dim3(32, 8), 256, 0, stream>>>(XT, eWih, eWhh, ebih, ebhh,
                                              Hin, Hout, ws + OFF_CT, t);
  }
  init2<<<1, 512, 0, stream>>>(ws);
  decoder<<<NWG, 1024, 0, stream>>>(in0, dWih, dWhh, dbih, dbhh, ws);
  out_proj<<<256, 128, 0, stream>>>(ws, linW, linb, out);
}

// Round 2
// 28654.877 us; speedup vs baseline: 5.7961x; 5.7961x over previous
//
#include <hip/hip_runtime.h>
#include <math.h>

#define A_ 64
#define B_ 256
#define D_ 128
#define H_ 512
#define STOT 16384
#define NWG 32

// workspace layout (float offsets)
#define OFF_XT    0
#define N_XT      (A_*D_*B_)              // 2097152 floats: transposed input [t][k][b]
#define OFF_HT0   (OFF_XT + N_XT)         // encoder h ping  [j][b]
#define OFF_HT1   (OFF_HT0 + H_*B_)       // encoder h pong
#define OFF_CT    (OFF_HT1 + H_*B_)       // encoder c       [j][b]
#define OFF_HTAP  (OFF_CT + H_*B_)        // decoder h taps  [256][512]
#define OFF_HB64  (OFF_HTAP + B_*H_)      // decoder tagged h, [2][512] x u64 (2048 floats)
#define OFF_CINIT (OFF_HB64 + 4*H_)       // decoder initial c [512]

__device__ __forceinline__ float sigf(float x) {
  return __builtin_amdgcn_rcpf(1.0f + __expf(-x));
}
// tanh(x) = 1 - 2/(e^{2x}+1); exact at saturation, ~1e-7 rel err mid-range
__device__ __forceinline__ float tanhfast(float x) {
  return 1.0f - 2.0f * __builtin_amdgcn_rcpf(__expf(2.0f * x) + 1.0f);
}

// ---------------------------------------------------------------------------
// init1: transpose input to XT[t][k][b], zero encoder h0/c0
// ---------------------------------------------------------------------------
__global__ void init1(const float* __restrict__ in0, float* __restrict__ ws) {
  float* XT  = ws + OFF_XT;
  float* HT0 = ws + OFF_HT0;
  float* CT  = ws + OFF_CT;
  int stride = gridDim.x * blockDim.x;
  for (int idx = blockIdx.x * blockDim.x + threadIdx.x; idx < N_XT; idx += stride) {
    int t = idx >> 15;
    int k = (idx >> 8) & 127;
    int b = idx & 255;
    XT[idx] = in0[t * (B_ * D_) + b * D_ + k];
    if (idx < H_ * B_) { HT0[idx] = 0.f; CT[idx] = 0.f; }
  }
}

// ---------------------------------------------------------------------------
// enc_step: one encoder LSTM timestep, fused GEMM (256x2048x640) + update.
// (unchanged from round 0 — passed; decoder dominates runtime)
// ---------------------------------------------------------------------------
__global__ __launch_bounds__(256) void enc_step(
    const float* __restrict__ XT, const float* __restrict__ Wih,
    const float* __restrict__ Whh, const float* __restrict__ bih,
    const float* __restrict__ bhh, const float* __restrict__ Hin,
    float* __restrict__ Hout, float* __restrict__ C, int t) {
  __shared__ float Wt[16 * 68];
  __shared__ float XHt[16 * 32];
  __shared__ float gs[64 * 33];
  const int tid = threadIdx.x;
  const int jt = blockIdx.x;
  const int bt = blockIdx.y;
  const int rr = tid >> 4;
  const int bb = tid & 15;

  float acc[4][2];
#pragma unroll
  for (int i = 0; i < 4; ++i) {
    int r = 4 * rr + i;
    int Row = ((r >> 4) << 9) + (jt << 4) + (r & 15);
    float bv = bih[Row] + bhh[Row];
    acc[i][0] = bv; acc[i][1] = bv;
  }

  for (int kt = 0; kt < 40; ++kt) {
    int k0 = kt << 4;
    __syncthreads();
#pragma unroll
    for (int e = 0; e < 4; ++e) {
      int idx = tid + (e << 8);
      int kk = idx & 15, r = idx >> 4;
      int Row = ((r >> 4) << 9) + (jt << 4) + (r & 15);
      int k = k0 + kk;
      float v = (k < D_) ? Wih[Row * D_ + k] : Whh[Row * H_ + (k - D_)];
      Wt[kk * 68 + r] = v;
    }
#pragma unroll
    for (int e = 0; e < 2; ++e) {
      int idx = tid + (e << 8);
      int kk = idx >> 5, b = idx & 31;
      int k = k0 + kk;
      int gb = (bt << 5) + b;
      float v = (k < D_) ? XT[(t * D_ + k) * B_ + gb] : Hin[(k - D_) * B_ + gb];
      XHt[kk * 32 + b] = v;
    }
    __syncthreads();
#pragma unroll
    for (int kk = 0; kk < 16; ++kk) {
      const float4 wv = *(const float4*)&Wt[kk * 68 + 4 * rr];
      const float2 xv = *(const float2*)&XHt[kk * 32 + 2 * bb];
      acc[0][0] += wv.x * xv.x; acc[0][1] += wv.x * xv.y;
      acc[1][0] += wv.y * xv.x; acc[1][1] += wv.y * xv.y;
      acc[2][0] += wv.z * xv.x; acc[2][1] += wv.z * xv.y;
      acc[3][0] += wv.w * xv.x; acc[3][1] += wv.w * xv.y;
    }
  }
  __syncthreads();
#pragma unroll
  for (int i = 0; i < 4; ++i) {
    gs[(4 * rr + i) * 33 + 2 * bb]     = acc[i][0];
    gs[(4 * rr + i) * 33 + 2 * bb + 1] = acc[i][1];
  }
  __syncthreads();
#pragma unroll
  for (int e = 0; e < 2; ++e) {
    int idx = tid + (e << 8);
    int jj = idx >> 5, b = idx & 31;
    int gb = (bt << 5) + b;
    float iv = gs[jj * 33 + b];
    float fv = gs[(16 + jj) * 33 + b];
    float gv = gs[(32 + jj) * 33 + b];
    float ov = gs[(48 + jj) * 33 + b];
    int addr = ((jt << 4) + jj) * B_ + gb;
    float c = C[addr];
    c = sigf(fv) * c + sigf(iv) * tanhf(gv);
    C[addr] = c;
    Hout[addr] = sigf(ov) * tanhf(c);
  }
}

// ---------------------------------------------------------------------------
// init2: seed decoder tagged h (tag 0, parity 1), invalidate parity 0,
// seed c, write HTAP[0] = initial decoder h.
// ---------------------------------------------------------------------------
__global__ void init2(float* __restrict__ ws) {
  const float* Hfin = ws + OFF_HT0;   // after 64 steps final h lands in HT0
  const float* CT   = ws + OFF_CT;
  unsigned long long* HB = (unsigned long long*)(ws + OFF_HB64);
  float* CIN  = ws + OFF_CINIT;
  float* HTAP = ws + OFF_HTAP;
  int j = threadIdx.x;                // 512 threads
  float hj = Hfin[j * B_ + 255];
  HB[H_ + j] = (unsigned long long)__float_as_uint(hj);  // tag 0 in high word
  HB[j] = 0xFFFFFFFF00000000ull;                         // invalid tag
  CIN[j]  = CT[j * B_ + 255];
  HTAP[j] = hj;
}

// ---------------------------------------------------------------------------
// decoder: persistent kernel, 32 WGs x 1024 threads, 16384 sequential steps.
// Sync protocol: NO fences, NO acquire/release. Each h element is a 64-bit
// (tag<<32 | float) relaxed agent-scope atom, double-buffered by parity.
// Tag == step index of the consumer. Wave v polls only its own 32 elements;
// one __syncthreads per step (partials -> wave-0 reduce).
// Overwrite safety: WG publishing step s+1 requires all its 16 waves passed
// their polls, which cover all 32 producer WGs at step s => any write of
// parity p at step s+2 happens after every WG (incl. this one) finished
// reading parity p at step s.
// ---------------------------------------------------------------------------
__global__ __launch_bounds__(1024) void decoder(
    const float* __restrict__ in0, const float* __restrict__ Wih,
    const float* __restrict__ Whh, const float* __restrict__ bih,
    const float* __restrict__ bhh, float* __restrict__ ws) {
  unsigned long long* HB = (unsigned long long*)(ws + OFF_HB64);
  float* HTAP = ws + OFF_HTAP;
  const float* CIN = ws + OFF_CINIT;

  __shared__ float part[2][16 * 64];  // [parity][wave][row]
  __shared__ float hstage[H_];        // per-wave private 32-float chunks

  const int tid = threadIdx.x;
  const int w = blockIdx.x;
  const int v = tid >> 6;             // wave -> k-chunk [32v, 32v+32)
  const int l = tid & 63;             // lane -> local gate row
  const int R = ((l >> 4) << 9) + (w << 4) + (l & 15);  // global gate row

  float4 wa[8];
#pragma unroll
  for (int k = 0; k < 8; ++k)
    wa[k] = *(const float4*)&Whh[R * H_ + (v << 5) + 4 * k];
  float4 wx0 = *(const float4*)&Wih[R * D_ + (v << 3)];
  float4 wx1 = *(const float4*)&Wih[R * D_ + (v << 3) + 4];

  float bias = 0.f, c = 0.f;
  if (v == 0) {                       // wave 0 holds bias (per row) and c
    bias = bih[R] + bhh[R];
    if (l < 16) c = CIN[(w << 4) + l];
  }

  const int pe = (v << 5) + (l & 31); // polled element (2 lanes per element)

  for (int s = 0; s < STOT; ++s) {
    // x loads — independent of h, issued before the poll to overlap
    const int tt = s & 63;
    const int bc = 255 - (s >> 6);
    const float* xp = in0 + (tt * B_ + bc) * D_ + (v << 3);
    float4 x0 = *(const float4*)xp;
    float4 x1 = *(const float4*)(xp + 4);

    // poll h_{s-1}: relaxed 64-bit tagged loads, no cache maintenance
    const unsigned long long* slot = &HB[(((s + 1) & 1) << 9) + pe];
    unsigned long long pk;
    for (;;) {
      pk = __hip_atomic_load(slot, __ATOMIC_RELAXED, __HIP_MEMORY_SCOPE_AGENT);
      if (__all((unsigned)(pk >> 32) == (unsigned)s)) break;
    }
    if (l < 32) hstage[pe] = __uint_as_float((unsigned)pk);

    float p = wx0.x * x0.x + wx0.y * x0.y + wx0.z * x0.z + wx0.w * x0.w
            + wx1.x * x1.x + wx1.y * x1.y + wx1.z * x1.z + wx1.w * x1.w;

    const float4* hp = (const float4*)&hstage[v << 5];
#pragma unroll
    for (int k = 0; k < 8; ++k) {
      float4 h4 = hp[k];
      p += wa[k].x * h4.x + wa[k].y * h4.y + wa[k].z * h4.z + wa[k].w * h4.w;
    }
    part[s & 1][(v << 6) + l] = p;
    __syncthreads();

    if (v == 0) {
      float g = bias;
#pragma unroll
      for (int j = 0; j < 16; ++j) g += part[s & 1][(j << 6) + l];
      // gather i,f,g,o for element e = l&15 from lanes e, e+16, e+32, e+48
      const int e = l & 15;
      float vi = __shfl(g, e);
      float vf = __shfl(g, e + 16);
      float vg = __shfl(g, e + 32);
      float vo = __shfl(g, e + 48);
      if (l < 16) {
        c = sigf(vf) * c + sigf(vi) * tanhfast(vg);
        float hn = sigf(vo) * tanhfast(c);
        if ((s & 63) == 63) {
          int q = (s >> 6) + 1;
          if (q < 256) HTAP[q * H_ + (w << 4) + l] = hn;
        }
        unsigned long long opk =
            ((unsigned long long)(unsigned)(s + 1) << 32) | __float_as_uint(hn);
        __hip_atomic_store(&HB[((s & 1) << 9) + (w << 4) + l], opk,
                           __ATOMIC_RELAXED, __HIP_MEMORY_SCOPE_AGENT);
      }
    }
  }
}

// ---------------------------------------------------------------------------
// out_proj: outs[255-b] = Htap[255-b] @ lin_W^T + lin_b, broadcast over a.
// ---------------------------------------------------------------------------
__global__ __launch_bounds__(128) void out_proj(
    const float* __restrict__ ws, const float* __restrict__ linW,
    const float* __restrict__ linb, float* __restrict__ out) {
  const float* HTAP = ws + OFF_HTAP;
  __shared__ float hs[H_];
  const int b = blockIdx.x;
  const int i = 255 - b;
  const int d = threadIdx.x;
  *(float4*)&hs[4 * d] = *(const float4*)&HTAP[i * H_ + 4 * d];
  __syncthreads();
  float acc = linb[d];
#pragma unroll 8
  for (int k = 0; k < H_; k += 4) {
    float4 w4 = *(const float4*)&linW[d * H_ + k];
    acc += w4.x * hs[k] + w4.y * hs[k + 1] + w4.z * hs[k + 2] + w4.w * hs[k + 3];
  }
  for (int a = 0; a < A_; ++a)
    out[(a * B_ + b) * D_ + d] = acc;
}

// ---------------------------------------------------------------------------
extern "C" void kernel_launch(void* const* d_in, const int* in_sizes, int n_in,
                              void* d_out, int out_size, void* d_ws, size_t ws_size,
                              hipStream_t stream) {
  const float* in0  = (const float*)d_in[0];
  const float* eWih = (const float*)d_in[1];
  const float* eWhh = (const float*)d_in[2];
  const float* ebih = (const float*)d_in[3];
  const float* ebhh = (const float*)d_in[4];
  const float* dWih = (const float*)d_in[5];
  const float* dWhh = (const float*)d_in[6];
  const float* dbih = (const float*)d_in[7];
  const float* dbhh = (const float*)d_in[8];
  const float* linW = (const float*)d_in[9];
  const float* linb = (const float*)d_in[10];
  float* ws = (float*)d_ws;
  float* out = (float*)d_out;

  init1<<<2048, 256, 0, stream>>>(in0, ws);

  const float* XT = ws + OFF_XT;
  for (int t = 0; t < 64; ++t) {
    float* Hin  = ws + ((t & 1) ? OFF_HT1 : OFF_HT0);
    float* Hout = ws + ((t & 1) ? OFF_HT0 : OFF_HT1);
    enc_step<<<dim3(32, 8), 256, 0, stream>>>(XT, eWih, eWhh, ebih, ebhh,
                                              Hin, Hout, ws + OFF_CT, t);
  }
  init2<<<1, 512, 0, stream>>>(ws);
  decoder<<<NWG, 1024, 0, stream>>>(in0, dWih, dWhh, dbih, dbhh, ws);
  out_proj<<<256, 128, 0, stream>>>(ws, linW, linb, out);
}

// Round 5
// 25762.436 us; speedup vs baseline: 6.4469x; 1.1123x over previous
//
#include <hip/hip_runtime.h>
#include <math.h>

#define A_ 64
#define B_ 256
#define D_ 128
#define H_ 512
#define STOT 16384
#define NWG 32

// s_getreg immediate: id | offset<<6 | (width-1)<<11 ; HW_REG_XCC_ID = 20
#define XCC_GETREG_IMM (20 | (31 << 11))

// workspace layout (float offsets)
#define OFF_XT    0
#define N_XT      (A_*D_*B_)              // transposed input [t][k][b]
#define OFF_HT0   (OFF_XT + N_XT)         // encoder h ping  [j][b]
#define OFF_HT1   (OFF_HT0 + H_*B_)       // encoder h pong
#define OFF_CT    (OFF_HT1 + H_*B_)       // encoder c       [j][b]
#define OFF_HTAP  (OFF_CT + H_*B_)        // decoder h taps  [256][512]
#define OFF_HB64  (OFF_HTAP + B_*H_)      // tagged h (L2 fast path)  [2][512] u64
#define OFF_HB2   (OFF_HB64 + 4*H_)       // tagged h (agent shadow)  [2][512] u64
#define OFF_CINIT (OFF_HB2 + 4*H_)        // decoder initial c [512]
#define OFF_ELECT (OFF_CINIT + H_)        // ints: [0..7] per-XCD counters, [8] winner

__device__ __forceinline__ float sigf(float x) {
  return __builtin_amdgcn_rcpf(1.0f + __expf(-x));
}
// tanh(x) = 1 - 2/(e^{2x}+1); exact at saturation
__device__ __forceinline__ float tanhfast(float x) {
  return 1.0f - 2.0f * __builtin_amdgcn_rcpf(__expf(2.0f * x) + 1.0f);
}

// ---------------------------------------------------------------------------
// init1: transpose input to XT[t][k][b], zero encoder h0/c0
// ---------------------------------------------------------------------------
__global__ void init1(const float* __restrict__ in0, float* __restrict__ ws) {
  float* XT  = ws + OFF_XT;
  float* HT0 = ws + OFF_HT0;
  float* CT  = ws + OFF_CT;
  int stride = gridDim.x * blockDim.x;
  for (int idx = blockIdx.x * blockDim.x + threadIdx.x; idx < N_XT; idx += stride) {
    int t = idx >> 15;
    int k = (idx >> 8) & 127;
    int b = idx & 255;
    XT[idx] = in0[t * (B_ * D_) + b * D_ + k];
    if (idx < H_ * B_) { HT0[idx] = 0.f; CT[idx] = 0.f; }
  }
}

// ---------------------------------------------------------------------------
// enc_step: one encoder LSTM timestep, fused GEMM (256x2048x640) + update.
// ---------------------------------------------------------------------------
__global__ __launch_bounds__(256) void enc_step(
    const float* __restrict__ XT, const float* __restrict__ Wih,
    const float* __restrict__ Whh, const float* __restrict__ bih,
    const float* __restrict__ bhh, const float* __restrict__ Hin,
    float* __restrict__ Hout, float* __restrict__ C, int t) {
  __shared__ float Wt[16 * 68];
  __shared__ float XHt[16 * 32];
  __shared__ float gs[64 * 33];
  const int tid = threadIdx.x;
  const int jt = blockIdx.x;
  const int bt = blockIdx.y;
  const int rr = tid >> 4;
  const int bb = tid & 15;

  float acc[4][2];
#pragma unroll
  for (int i = 0; i < 4; ++i) {
    int r = 4 * rr + i;
    int Row = ((r >> 4) << 9) + (jt << 4) + (r & 15);
    float bv = bih[Row] + bhh[Row];
    acc[i][0] = bv; acc[i][1] = bv;
  }

  for (int kt = 0; kt < 40; ++kt) {
    int k0 = kt << 4;
    __syncthreads();
#pragma unroll
    for (int e = 0; e < 4; ++e) {
      int idx = tid + (e << 8);
      int kk = idx & 15, r = idx >> 4;
      int Row = ((r >> 4) << 9) + (jt << 4) + (r & 15);
      int k = k0 + kk;
      float v = (k < D_) ? Wih[Row * D_ + k] : Whh[Row * H_ + (k - D_)];
      Wt[kk * 68 + r] = v;
    }
#pragma unroll
    for (int e = 0; e < 2; ++e) {
      int idx = tid + (e << 8);
      int kk = idx >> 5, b = idx & 31;
      int k = k0 + kk;
      int gb = (bt << 5) + b;
      float v = (k < D_) ? XT[(t * D_ + k) * B_ + gb] : Hin[(k - D_) * B_ + gb];
      XHt[kk * 32 + b] = v;
    }
    __syncthreads();
#pragma unroll
    for (int kk = 0; kk < 16; ++kk) {
      const float4 wv = *(const float4*)&Wt[kk * 68 + 4 * rr];
      const float2 xv = *(const float2*)&XHt[kk * 32 + 2 * bb];
      acc[0][0] += wv.x * xv.x; acc[0][1] += wv.x * xv.y;
      acc[1][0] += wv.y * xv.x; acc[1][1] += wv.y * xv.y;
      acc[2][0] += wv.z * xv.x; acc[2][1] += wv.z * xv.y;
      acc[3][0] += wv.w * xv.x; acc[3][1] += wv.w * xv.y;
    }
  }
  __syncthreads();
#pragma unroll
  for (int i = 0; i < 4; ++i) {
    gs[(4 * rr + i) * 33 + 2 * bb]     = acc[i][0];
    gs[(4 * rr + i) * 33 + 2 * bb + 1] = acc[i][1];
  }
  __syncthreads();
#pragma unroll
  for (int e = 0; e < 2; ++e) {
    int idx = tid + (e << 8);
    int jj = idx >> 5, b = idx & 31;
    int gb = (bt << 5) + b;
    float iv = gs[jj * 33 + b];
    float fv = gs[(16 + jj) * 33 + b];
    float gv = gs[(32 + jj) * 33 + b];
    float ov = gs[(48 + jj) * 33 + b];
    int addr = ((jt << 4) + jj) * B_ + gb;
    float c = C[addr];
    c = sigf(fv) * c + sigf(iv) * tanhf(gv);
    C[addr] = c;
    Hout[addr] = sigf(ov) * tanhf(c);
  }
}

// ---------------------------------------------------------------------------
// init2: seed both tagged h buffers (tag 0 in parity 1, invalid in parity 0),
// seed c, HTAP[0], reset election. Visible to decoder via end-of-kernel flush.
// ---------------------------------------------------------------------------
__global__ void init2(float* __restrict__ ws) {
  const float* Hfin = ws + OFF_HT0;   // after 64 steps final h lands in HT0
  const float* CT   = ws + OFF_CT;
  unsigned long long* HB  = (unsigned long long*)(ws + OFF_HB64);
  unsigned long long* HB2 = (unsigned long long*)(ws + OFF_HB2);
  float* CIN  = ws + OFF_CINIT;
  float* HTAP = ws + OFF_HTAP;
  int* EL     = (int*)(ws + OFF_ELECT);
  int j = threadIdx.x;                // 512 threads
  float hj = Hfin[j * B_ + 255];
  unsigned long long seed = (unsigned long long)__float_as_uint(hj);
  HB[H_ + j]  = seed;                 // tag 0, parity 1
  HB[j]       = 0xFFFFFFFF00000000ull;
  HB2[H_ + j] = seed;
  HB2[j]      = 0xFFFFFFFF00000000ull;
  CIN[j]  = CT[j * B_ + 255];
  HTAP[j] = hj;
  if (j < 8) EL[j] = 0;
  if (j == 8) EL[8] = -1;             // winner xcd
}

// ---------------------------------------------------------------------------
// decoder: 256 WGs launched; the 32 on one elected XCD run 16384 sequential
// steps. Fast path: publish = plain write-through store (L1 is write-through
// => lands in the shared XCD L2); poll = buffer_inv sc0 (L1 invalidate) +
// plain volatile load (L2-served, ~200cy). Safety net: every slot is also
// published via relaxed AGENT atomics to a shadow buffer; a wave that spins
// >256 iterations permanently escalates to agent polls (round-2 protocol) —
// deadlock-free even if XCD election or cache semantics are wrong.
// ---------------------------------------------------------------------------
__global__ __launch_bounds__(1024) void decoder(
    const float* __restrict__ in0, const float* __restrict__ Wih,
    const float* __restrict__ Whh, const float* __restrict__ bih,
    const float* __restrict__ bhh, float* __restrict__ ws) {
  unsigned long long* HB  = (unsigned long long*)(ws + OFF_HB64);
  unsigned long long* HB2 = (unsigned long long*)(ws + OFF_HB2);
  float* HTAP = ws + OFF_HTAP;
  const float* CIN = ws + OFF_CINIT;

  __shared__ float part[2][16 * 64];  // [parity][wave][row]
  __shared__ float hstage[H_];
  __shared__ int role;

  const int tid = threadIdx.x;

  // ---- election: first XCD to seat 32 WGs wins; its ranks 0..31 decode ----
  if (tid == 0) {
    unsigned xcc = ((unsigned)__builtin_amdgcn_s_getreg(XCC_GETREG_IMM)) & 7u;
    int* EL = (int*)(ws + OFF_ELECT);
    int r = __hip_atomic_fetch_add(&EL[xcc], 1, __ATOMIC_RELAXED,
                                   __HIP_MEMORY_SCOPE_AGENT);
    int myrole = -1;
    if (r < NWG) {
      if (r == NWG - 1) {
        int exp = -1;
        __hip_atomic_compare_exchange_strong(&EL[8], &exp, (int)xcc,
            __ATOMIC_RELAXED, __ATOMIC_RELAXED, __HIP_MEMORY_SCOPE_AGENT);
      }
      int wx;
      do {
        wx = __hip_atomic_load(&EL[8], __ATOMIC_RELAXED, __HIP_MEMORY_SCOPE_AGENT);
        if (wx == -1) __builtin_amdgcn_s_sleep(2);
      } while (wx == -1);
      if (wx == (int)xcc) myrole = r;
    }
    role = myrole;
  }
  __syncthreads();
  if (role < 0) return;               // uniform per WG
  const int w = role;

  const int v = tid >> 6;             // wave -> k-chunk [32v, 32v+32)
  const int l = tid & 63;             // lane -> local gate row
  const int R = ((l >> 4) << 9) + (w << 4) + (l & 15);  // global gate row

  float4 wa[8];
#pragma unroll
  for (int k = 0; k < 8; ++k)
    wa[k] = *(const float4*)&Whh[R * H_ + (v << 5) + 4 * k];
  float4 wx0 = *(const float4*)&Wih[R * D_ + (v << 3)];
  float4 wx1 = *(const float4*)&Wih[R * D_ + (v << 3) + 4];

  float bias = 0.f, c = 0.f;
  if (v == 0) {                       // wave 0 holds bias (per row) and c
    bias = bih[R] + bhh[R];
    if (l < 16) c = CIN[(w << 4) + l];
  }

  const int pe = (v << 5) + (l & 31); // polled element (2 lanes per element)
  int escal = 0;                      // wave-uniform sticky escalation flag

  for (int s = 0; s < STOT; ++s) {
    // x loads — independent of h, issued before the poll to overlap
    const int tt = s & 63;
    const int bc = 255 - (s >> 6);
    const float* xp = in0 + (tt * B_ + bc) * D_ + (v << 3);
    float4 x0 = *(const float4*)xp;
    float4 x1 = *(const float4*)(xp + 4);

    const int slotIdx = (((s + 1) & 1) << 9) + pe;
    unsigned long long pk = 0;
    if (!escal) {
      int spins = 0;
      for (;;) {
        asm volatile("buffer_inv sc0" ::: "memory");  // invalidate own L1
        pk = *(volatile const unsigned long long*)&HB[slotIdx];
        if (__all((unsigned)(pk >> 32) == (unsigned)s)) break;
        if (++spins > 256) { escal = 1; break; }      // wave-uniform
      }
    }
    if (escal) {                      // agent-scope fallback (round-2 path)
      for (;;) {
        pk = __hip_atomic_load(&HB2[slotIdx], __ATOMIC_RELAXED,
                               __HIP_MEMORY_SCOPE_AGENT);
        if (__all((unsigned)(pk >> 32) == (unsigned)s)) break;
        __builtin_amdgcn_s_sleep(1);
      }
    }
    if (l < 32) hstage[pe] = __uint_as_float((unsigned)pk);

    float p = wx0.x * x0.x + wx0.y * x0.y + wx0.z * x0.z + wx0.w * x0.w
            + wx1.x * x1.x + wx1.y * x1.y + wx1.z * x1.z + wx1.w * x1.w;

    const float4* hp = (const float4*)&hstage[v << 5];
#pragma unroll
    for (int k = 0; k < 8; ++k) {
      float4 h4 = hp[k];
      p += wa[k].x * h4.x + wa[k].y * h4.y + wa[k].z * h4.z + wa[k].w * h4.w;
    }
    part[s & 1][(v << 6) + l] = p;
    __syncthreads();

    if (v == 0) {
      float g = bias;
#pragma unroll
      for (int j = 0; j < 16; ++j) g += part[s & 1][(j << 6) + l];
      const int e = l & 15;
      float vi = __shfl(g, e);
      float vf = __shfl(g, e + 16);
      float vg = __shfl(g, e + 32);
      float vo = __shfl(g, e + 48);
      if (l < 16) {
        c = sigf(vf) * c + sigf(vi) * tanhfast(vg);
        float hn = sigf(vo) * tanhfast(c);
        if ((s & 63) == 63) {
          int q = (s >> 6) + 1;
          if (q < 256) HTAP[q * H_ + (w << 4) + l] = hn;
        }
        unsigned long long opk =
            ((unsigned long long)(unsigned)(s + 1) << 32) | __float_as_uint(hn);
        const int oIdx = ((s & 1) << 9) + (w << 4) + l;
        // fast path: plain write-through store -> shared XCD L2
        *(volatile unsigned long long*)&HB[oIdx] = opk;
        // shadow: agent-scope store -> LLC (fallback consumers)
        __hip_atomic_store(&HB2[oIdx], opk, __ATOMIC_RELAXED,
                           __HIP_MEMORY_SCOPE_AGENT);
      }
    }
  }
}

// ---------------------------------------------------------------------------
// out_proj: outs[255-b] = Htap[255-b] @ lin_W^T + lin_b, broadcast over a.
// ---------------------------------------------------------------------------
__global__ __launch_bounds__(128) void out_proj(
    const float* __restrict__ ws, const float* __restrict__ linW,
    const float* __restrict__ linb, float* __restrict__ out) {
  const float* HTAP = ws + OFF_HTAP;
  __shared__ float hs[H_];
  const int b = blockIdx.x;
  const int i = 255 - b;
  const int d = threadIdx.x;
  *(float4*)&hs[4 * d] = *(const float4*)&HTAP[i * H_ + 4 * d];
  __syncthreads();
  float acc = linb[d];
#pragma unroll 8
  for (int k = 0; k < H_; k += 4) {
    float4 w4 = *(const float4*)&linW[d * H_ + k];
    acc += w4.x * hs[k] + w4.y * hs[k + 1] + w4.z * hs[k + 2] + w4.w * hs[k + 3];
  }
  for (int a = 0; a < A_; ++a)
    out[(a * B_ + b) * D_ + d] = acc;
}

// ---------------------------------------------------------------------------
extern "C" void kernel_launch(void* const* d_in, const int* in_sizes, int n_in,
                              void* d_out, int out_size, void* d_ws, size_t ws_size,
                              hipStream_t stream) {
  const float* in0  = (const float*)d_in[0];
  const float* eWih = (const float*)d_in[1];
  const float* eWhh = (const float*)d_in[2];
  const float* ebih = (const float*)d_in[3];
  const float* ebhh = (const float*)d_in[4];
  const float* dWih = (const float*)d_in[5];
  const float* dWhh = (const float*)d_in[6];
  const float* dbih = (const float*)d_in[7];
  const float* dbhh = (const float*)d_in[8];
  const float* linW = (const float*)d_in[9];
  const float* linb = (const float*)d_in[10];
  float* ws = (float*)d_ws;
  float* out = (float*)d_out;

  init1<<<2048, 256, 0, stream>>>(in0, ws);

  const float* XT = ws + OFF_XT;
  for (int t = 0; t < 64; ++t) {
    float* Hin  = ws + ((t & 1) ? OFF_HT1 : OFF_HT0);
    float* Hout = ws + ((t & 1) ? OFF_HT0 : OFF_HT1);
    enc_step<<<dim3(32, 8), 256, 0, stream>>>(XT, eWih, eWhh, ebih, ebhh,
                                              Hin, Hout, ws + OFF_CT, t);
  }
  init2<<<1, 512, 0, stream>>>(ws);
  decoder<<<256, 1024, 0, stream>>>(in0, dWih, dWhh, dbih, dbhh, ws);
  out_proj<<<256, 128, 0, stream>>>(ws, linW, linb, out);
}

// Round 6
// 22329.492 us; speedup vs baseline: 7.4380x; 1.1537x over previous
//
#include <hip/hip_runtime.h>
#include <math.h>

#define A_ 64
#define B_ 256
#define D_ 128
#define H_ 512
#define STOT 16384
#define NWG 32

// s_getreg immediate: id | offset<<6 | (width-1)<<11 ; HW_REG_XCC_ID = 20
#define XCC_GETREG_IMM (20 | (31 << 11))

// workspace layout (float offsets)
#define OFF_XT    0
#define N_XT      (A_*D_*B_)              // transposed input [t][k][b]
#define OFF_HT0   (OFF_XT + N_XT)         // encoder h ping  [j][b]
#define OFF_HT1   (OFF_HT0 + H_*B_)       // encoder h pong
#define OFF_CT    (OFF_HT1 + H_*B_)       // encoder c       [j][b]
#define OFF_HTAP  (OFF_CT + H_*B_)        // decoder h taps  [256][512]
#define OFF_HB64  (OFF_HTAP + B_*H_)      // tagged h [2][512] u64
#define OFF_CINIT (OFF_HB64 + 4*H_)       // decoder initial c [512]
#define OFF_ELECT (OFF_CINIT + H_)        // ints: [0..7] per-XCD counters, [8] winner

__device__ __forceinline__ float sigf(float x) {
  return __builtin_amdgcn_rcpf(1.0f + __expf(-x));
}
// tanh(x) = 1 - 2/(e^{2x}+1); exact at saturation
__device__ __forceinline__ float tanhfast(float x) {
  return 1.0f - 2.0f * __builtin_amdgcn_rcpf(__expf(2.0f * x) + 1.0f);
}

// nt load: no L1 allocation => never hits a stale L1 line; served by the
// XCD-shared L2 (~200cy) since all decoder WGs are elected onto one XCD.
// "=&v" early-clobber: dest must not alias the address pair (round-3 lesson).
__device__ __forceinline__ unsigned long long load_nt(const unsigned long long* p) {
  unsigned long long v;
  asm volatile("global_load_dwordx2 %0, %1, off nt\n\ts_waitcnt vmcnt(0)"
               : "=&v"(v) : "v"(p) : "memory");
  return v;
}
// liveness fallback (round-5-proven): L1 invalidate + load. Used 1/64 spins.
__device__ __forceinline__ unsigned long long load_inv(const unsigned long long* p) {
  unsigned long long v;
  asm volatile("buffer_inv sc0\n\t"
               "global_load_dwordx2 %0, %1, off nt\n\ts_waitcnt vmcnt(0)"
               : "=&v"(v) : "v"(p) : "memory");
  return v;
}
// nt store: write-through to shared L2, no L1 allocate, fast ack (keeps the
// producer wave's vmcnt drain cheap — round-5's agent shadow store was the
// hidden ~900cy/step stall on wave0).
__device__ __forceinline__ void store_nt(unsigned long long* p, unsigned long long v) {
  asm volatile("global_store_dwordx2 %0, %1, off nt" :: "v"(p), "v"(v) : "memory");
}

// ---------------------------------------------------------------------------
// init1: transpose input to XT[t][k][b], zero encoder h0/c0
// ---------------------------------------------------------------------------
__global__ void init1(const float* __restrict__ in0, float* __restrict__ ws) {
  float* XT  = ws + OFF_XT;
  float* HT0 = ws + OFF_HT0;
  float* CT  = ws + OFF_CT;
  int stride = gridDim.x * blockDim.x;
  for (int idx = blockIdx.x * blockDim.x + threadIdx.x; idx < N_XT; idx += stride) {
    int t = idx >> 15;
    int k = (idx >> 8) & 127;
    int b = idx & 255;
    XT[idx] = in0[t * (B_ * D_) + b * D_ + k];
    if (idx < H_ * B_) { HT0[idx] = 0.f; CT[idx] = 0.f; }
  }
}

// ---------------------------------------------------------------------------
// enc_step: one encoder LSTM timestep, fused GEMM (256x2048x640) + update.
// ---------------------------------------------------------------------------
__global__ __launch_bounds__(256) void enc_step(
    const float* __restrict__ XT, const float* __restrict__ Wih,
    const float* __restrict__ Whh, const float* __restrict__ bih,
    const float* __restrict__ bhh, const float* __restrict__ Hin,
    float* __restrict__ Hout, float* __restrict__ C, int t) {
  __shared__ float Wt[16 * 68];
  __shared__ float XHt[16 * 32];
  __shared__ float gs[64 * 33];
  const int tid = threadIdx.x;
  const int jt = blockIdx.x;
  const int bt = blockIdx.y;
  const int rr = tid >> 4;
  const int bb = tid & 15;

  float acc[4][2];
#pragma unroll
  for (int i = 0; i < 4; ++i) {
    int r = 4 * rr + i;
    int Row = ((r >> 4) << 9) + (jt << 4) + (r & 15);
    float bv = bih[Row] + bhh[Row];
    acc[i][0] = bv; acc[i][1] = bv;
  }

  for (int kt = 0; kt < 40; ++kt) {
    int k0 = kt << 4;
    __syncthreads();
#pragma unroll
    for (int e = 0; e < 4; ++e) {
      int idx = tid + (e << 8);
      int kk = idx & 15, r = idx >> 4;
      int Row = ((r >> 4) << 9) + (jt << 4) + (r & 15);
      int k = k0 + kk;
      float v = (k < D_) ? Wih[Row * D_ + k] : Whh[Row * H_ + (k - D_)];
      Wt[kk * 68 + r] = v;
    }
#pragma unroll
    for (int e = 0; e < 2; ++e) {
      int idx = tid + (e << 8);
      int kk = idx >> 5, b = idx & 31;
      int k = k0 + kk;
      int gb = (bt << 5) + b;
      float v = (k < D_) ? XT[(t * D_ + k) * B_ + gb] : Hin[(k - D_) * B_ + gb];
      XHt[kk * 32 + b] = v;
    }
    __syncthreads();
#pragma unroll
    for (int kk = 0; kk < 16; ++kk) {
      const float4 wv = *(const float4*)&Wt[kk * 68 + 4 * rr];
      const float2 xv = *(const float2*)&XHt[kk * 32 + 2 * bb];
      acc[0][0] += wv.x * xv.x; acc[0][1] += wv.x * xv.y;
      acc[1][0] += wv.y * xv.x; acc[1][1] += wv.y * xv.y;
      acc[2][0] += wv.z * xv.x; acc[2][1] += wv.z * xv.y;
      acc[3][0] += wv.w * xv.x; acc[3][1] += wv.w * xv.y;
    }
  }
  __syncthreads();
#pragma unroll
  for (int i = 0; i < 4; ++i) {
    gs[(4 * rr + i) * 33 + 2 * bb]     = acc[i][0];
    gs[(4 * rr + i) * 33 + 2 * bb + 1] = acc[i][1];
  }
  __syncthreads();
#pragma unroll
  for (int e = 0; e < 2; ++e) {
    int idx = tid + (e << 8);
    int jj = idx >> 5, b = idx & 31;
    int gb = (bt << 5) + b;
    float iv = gs[jj * 33 + b];
    float fv = gs[(16 + jj) * 33 + b];
    float gv = gs[(32 + jj) * 33 + b];
    float ov = gs[(48 + jj) * 33 + b];
    int addr = ((jt << 4) + jj) * B_ + gb;
    float c = C[addr];
    c = sigf(fv) * c + sigf(iv) * tanhf(gv);
    C[addr] = c;
    Hout[addr] = sigf(ov) * tanhf(c);
  }
}

// ---------------------------------------------------------------------------
// init2: seed tagged h (tag 0 in parity 1, invalid in parity 0), seed c,
// HTAP[0], reset election.
// ---------------------------------------------------------------------------
__global__ void init2(float* __restrict__ ws) {
  const float* Hfin = ws + OFF_HT0;   // after 64 steps final h lands in HT0
  const float* CT   = ws + OFF_CT;
  unsigned long long* HB = (unsigned long long*)(ws + OFF_HB64);
  float* CIN  = ws + OFF_CINIT;
  float* HTAP = ws + OFF_HTAP;
  int* EL     = (int*)(ws + OFF_ELECT);
  int j = threadIdx.x;                // 512 threads
  float hj = Hfin[j * B_ + 255];
  HB[H_ + j] = (unsigned long long)__float_as_uint(hj);  // tag 0, parity 1
  HB[j]      = 0xFFFFFFFF00000000ull;
  CIN[j]  = CT[j * B_ + 255];
  HTAP[j] = hj;
  if (j < 8) EL[j] = 0;
  if (j == 8) EL[8] = -1;             // winner xcd
}

// ---------------------------------------------------------------------------
// decoder: 256 WGs launched; the 32 on one elected XCD run 16384 sequential
// steps; others exit. All handshake traffic is nt loads/stores served by the
// XCD-shared L2. One __syncthreads per step (before wave0's reduce); hstage
// is wave-private so needs no barrier. Poll falls back to buffer_inv+load
// every 64 spins (stateless liveness guarantee, round-5-proven semantics).
// ---------------------------------------------------------------------------
__global__ __launch_bounds__(1024) void decoder(
    const float* __restrict__ in0, const float* __restrict__ Wih,
    const float* __restrict__ Whh, const float* __restrict__ bih,
    const float* __restrict__ bhh, float* __restrict__ ws) {
  unsigned long long* HB = (unsigned long long*)(ws + OFF_HB64);
  float* HTAP = ws + OFF_HTAP;
  const float* CIN = ws + OFF_CINIT;

  __shared__ float part[2][16 * 64];  // [parity][wave][row]
  __shared__ float hstage[H_];        // wave-private 32-float chunks
  __shared__ int role;

  const int tid = threadIdx.x;

  // ---- election: first XCD to seat 32 WGs wins; its ranks 0..31 decode ----
  if (tid == 0) {
    unsigned xcc = ((unsigned)__builtin_amdgcn_s_getreg(XCC_GETREG_IMM)) & 7u;
    int* EL = (int*)(ws + OFF_ELECT);
    int r = __hip_atomic_fetch_add(&EL[xcc], 1, __ATOMIC_RELAXED,
                                   __HIP_MEMORY_SCOPE_AGENT);
    int myrole = -1;
    if (r < NWG) {
      if (r == NWG - 1) {
        int exp = -1;
        __hip_atomic_compare_exchange_strong(&EL[8], &exp, (int)xcc,
            __ATOMIC_RELAXED, __ATOMIC_RELAXED, __HIP_MEMORY_SCOPE_AGENT);
      }
      int wx;
      do {
        wx = __hip_atomic_load(&EL[8], __ATOMIC_RELAXED, __HIP_MEMORY_SCOPE_AGENT);
        if (wx == -1) __builtin_amdgcn_s_sleep(2);
      } while (wx == -1);
      if (wx == (int)xcc) myrole = r;
    }
    role = myrole;
  }
  __syncthreads();
  if (role < 0) return;               // uniform per WG
  const int w = role;

  const int v = tid >> 6;             // wave -> k-chunk [32v, 32v+32)
  const int l = tid & 63;             // lane -> local gate row
  const int R = ((l >> 4) << 9) + (w << 4) + (l & 15);  // global gate row

  float4 wa[8];
#pragma unroll
  for (int k = 0; k < 8; ++k)
    wa[k] = *(const float4*)&Whh[R * H_ + (v << 5) + 4 * k];
  float4 wx0 = *(const float4*)&Wih[R * D_ + (v << 3)];
  float4 wx1 = *(const float4*)&Wih[R * D_ + (v << 3) + 4];

  float bias = 0.f, c = 0.f;
  if (v == 0) {                       // wave 0 holds bias (per row) and c
    bias = bih[R] + bhh[R];
    if (l < 16) c = CIN[(w << 4) + l];
  }

  const int pe = (v << 5) + (l & 31); // polled element (2 lanes per element)

  for (int s = 0; s < STOT; ++s) {
    // x loads — independent of h, issued before the poll to overlap
    const int tt = s & 63;
    const int bc = 255 - (s >> 6);
    const float* xp = in0 + (tt * B_ + bc) * D_ + (v << 3);
    float4 x0 = *(const float4*)xp;
    float4 x1 = *(const float4*)(xp + 4);

    // poll h_{s-1}: nt loads from the shared L2; inv fallback 1/64 spins
    unsigned long long* slot = &HB[(((s + 1) & 1) << 9) + pe];
    unsigned long long pk;
    int spins = 0;
    for (;;) {
      pk = ((++spins & 63) == 0) ? load_inv(slot) : load_nt(slot);
      if (__all((unsigned)(pk >> 32) == (unsigned)s)) break;
    }
    if (l < 32) hstage[pe] = __uint_as_float((unsigned)pk);
    // intra-wave LDS dependency only: compiler's lgkmcnt wait suffices.

    float p = wx0.x * x0.x + wx0.y * x0.y + wx0.z * x0.z + wx0.w * x0.w
            + wx1.x * x1.x + wx1.y * x1.y + wx1.z * x1.z + wx1.w * x1.w;

    const float4* hp = (const float4*)&hstage[v << 5];
#pragma unroll
    for (int k = 0; k < 8; ++k) {
      float4 h4 = hp[k];                  // wave-uniform address: LDS broadcast
      p += wa[k].x * h4.x + wa[k].y * h4.y + wa[k].z * h4.z + wa[k].w * h4.w;
    }
    part[s & 1][(v << 6) + l] = p;
    __syncthreads();                      // the ONE barrier per step

    if (v == 0) {
      float g = bias;
#pragma unroll
      for (int j = 0; j < 16; ++j) g += part[s & 1][(j << 6) + l];
      const int e = l & 15;
      float vi = __shfl(g, e);
      float vf = __shfl(g, e + 16);
      float vg = __shfl(g, e + 32);
      float vo = __shfl(g, e + 48);
      if (l < 16) {
        c = sigf(vf) * c + sigf(vi) * tanhfast(vg);
        float hn = sigf(vo) * tanhfast(c);
        if ((s & 63) == 63) {
          int q = (s >> 6) + 1;
          if (q < 256) HTAP[q * H_ + (w << 4) + l] = hn;
        }
        unsigned long long opk =
            ((unsigned long long)(unsigned)(s + 1) << 32) | __float_as_uint(hn);
        store_nt(&HB[((s & 1) << 9) + (w << 4) + l], opk);
      }
    }
  }
}

// ---------------------------------------------------------------------------
// out_proj: outs[255-b] = Htap[255-b] @ lin_W^T + lin_b, broadcast over a.
// ---------------------------------------------------------------------------
__global__ __launch_bounds__(128) void out_proj(
    const float* __restrict__ ws, const float* __restrict__ linW,
    const float* __restrict__ linb, float* __restrict__ out) {
  const float* HTAP = ws + OFF_HTAP;
  __shared__ float hs[H_];
  const int b = blockIdx.x;
  const int i = 255 - b;
  const int d = threadIdx.x;
  *(float4*)&hs[4 * d] = *(const float4*)&HTAP[i * H_ + 4 * d];
  __syncthreads();
  float acc = linb[d];
#pragma unroll 8
  for (int k = 0; k < H_; k += 4) {
    float4 w4 = *(const float4*)&linW[d * H_ + k];
    acc += w4.x * hs[k] + w4.y * hs[k + 1] + w4.z * hs[k + 2] + w4.w * hs[k + 3];
  }
  for (int a = 0; a < A_; ++a)
    out[(a * B_ + b) * D_ + d] = acc;
}

// ---------------------------------------------------------------------------
extern "C" void kernel_launch(void* const* d_in, const int* in_sizes, int n_in,
                              void* d_out, int out_size, void* d_ws, size_t ws_size,
                              hipStream_t stream) {
  const float* in0  = (const float*)d_in[0];
  const float* eWih = (const float*)d_in[1];
  const float* eWhh = (const float*)d_in[2];
  const float* ebih = (const float*)d_in[3];
  const float* ebhh = (const float*)d_in[4];
  const float* dWih = (const float*)d_in[5];
  const float* dWhh = (const float*)d_in[6];
  const float* dbih = (const float*)d_in[7];
  const float* dbhh = (const float*)d_in[8];
  const float* linW = (const float*)d_in[9];
  const float* linb = (const float*)d_in[10];
  float* ws = (float*)d_ws;
  float* out = (float*)d_out;

  init1<<<2048, 256, 0, stream>>>(in0, ws);

  const float* XT = ws + OFF_XT;
  for (int t = 0; t < 64; ++t) {
    float* Hin  = ws + ((t & 1) ? OFF_HT1 : OFF_HT0);
    float* Hout = ws + ((t & 1) ? OFF_HT0 : OFF_HT1);
    enc_step<<<dim3(32, 8), 256, 0, stream>>>(XT, eWih, eWhh, ebih, ebhh,
                                              Hin, Hout, ws + OFF_CT, t);
  }
  init2<<<1, 512, 0, stream>>>(ws);
  decoder<<<256, 1024, 0, stream>>>(in0, dWih, dWhh, dbih, dbhh, ws);
  out_proj<<<256, 128, 0, stream>>>(ws, linW, linb, out);
}